// Round 12
// baseline (216.512 us; speedup 1.0000x reference)
//
#include <hip/hip_runtime.h>
#include <cstdint>

#define TICKS   1000
#define KH      7
#define KW      7
#define NTAPS   49
#define OUT_CH  128

#define BUF_ELEMS   (NTAPS * TICKS)      // 49000 floats at ws[0]
#define P_OFF_B     196608               // byte offset of P^T[c*1000+t] (128000 floats)
#define P_ELEMS     (OUT_CH * TICKS)
#define BINS_OFF_B  708608               // byte offset of class bins
#define HOT_OFF_B   1757184              // byte offset of per-block hot slabs
#define HOT_BINS    4000                 // 1000 ticks x 4 hot classes
#define HOT_SLAB_B  (HOT_BINS * 4)       // 16 KB per block
#define NBH_MAX     256
#define SH_THREADS  1024                 // r10: 256->1024 (r7 ran 1 wave/SIMD: latency-starved)

// x-classes: x<6 -> x exactly; x>=6 -> 6 + (x-6)%stride.  Validity of tap kx for
// class cx is (cx>=kx) && ((cx-kx)%stride==0) — exact for x<6; for x>=6, cx>=6>=kx
// always, and (x-kx) ≡ (cx-kx) (mod stride) since x ≡ cx (mod stride).
static __device__ __forceinline__ int num_classes(int stride) {
    int n = (KW - 1) + stride;
    return n > 128 ? 128 : n;
}

static __device__ __forceinline__ bool use_class(int stride, unsigned long long ws_size) {
    if (stride < 1) return false;
    long long nc = num_classes(stride);
    long long bytes = (long long)TICKS * nc * nc * 4;
    return (long long)BINS_OFF_B + bytes <= (long long)ws_size;
}

static __device__ __forceinline__ void scatter_event_cold(
        int t, int x, int y, float v, int stride, bool cls, int nc, float* ws) {
    float* buf  = ws;
    float* bins = (float*)((char*)ws + BINS_OFF_B);
    if (cls) {
        int cx = (x < KW - 1) ? x : (KW - 1) + (x - (KW - 1)) % stride;
        int cy = (y < KH - 1) ? y : (KH - 1) + (y - (KH - 1)) % stride;
        unsafeAtomicAdd(&bins[((long long)t * nc + cx) * nc + cy], v);
    } else {
        for (int ky = 0; ky < KH; ++ky) {
            int oy = y - ky;
            if (oy < 0 || (oy % stride) != 0) continue;
            for (int kx = 0; kx < KW; ++kx) {
                int ox = x - kx;
                if (ox < 0 || (ox % stride) != 0) continue;
                unsafeAtomicAdd(&buf[(ky * KW + kx) * TICKS + t], v);
            }
        }
    }
}

__global__ void zero_kernel(float* ws, const int* __restrict__ stride_p,
                            unsigned long long ws_size) {
    int stride = *stride_p;
    long long nbins = 0;
    if (use_class(stride, ws_size)) {
        long long nc = num_classes(stride);
        nbins = (long long)TICKS * nc * nc;
    }
    float* bins = (float*)((char*)ws + BINS_OFF_B);
    long long gid = (long long)blockIdx.x * blockDim.x + threadIdx.x;
    long long gsz = (long long)gridDim.x * blockDim.x;
    for (long long i = gid; i < BUF_ELEMS; i += gsz) ws[i] = 0.0f;
    for (long long i = gid; i < nbins; i += gsz) bins[i] = 0.0f;
}

// legacy path (ws too small for hot slabs): 1 global atomic / event
__global__ void scatter_kernel(const int* __restrict__ ticks, const int* __restrict__ xs,
                               const int* __restrict__ ys, const float* __restrict__ vals,
                               const int* __restrict__ stride_p, float* ws,
                               unsigned long long ws_size, int n) {
    int stride = *stride_p;
    bool cls = use_class(stride, ws_size);
    int nc = num_classes(stride);
    int gid = blockIdx.x * blockDim.x + threadIdx.x;
    if (gid >= n) return;
    scatter_event_cold(ticks[gid], xs[gid], ys[gid], vals[gid], stride, cls, nc, ws);
}

// Hot path: ~91% of events (stride<=2: x>=6 && y>=6) collapse onto <=4 classes
// per tick -> per-block LDS histogram, coalesced flush to private slab.
// r10: 1024 threads/block (16 waves/CU) — r7's 256-thread config was 1 wave/SIMD
// and latency-starved on the 24MB event stream (implied ~77us, no gain vs r6).
__global__ void __launch_bounds__(SH_THREADS) scatter_hot(
        const int* __restrict__ ticks, const int* __restrict__ xs,
        const int* __restrict__ ys, const float* __restrict__ vals,
        const int* __restrict__ stride_p, float* ws,
        unsigned long long ws_size, int n) {
    __shared__ float lds_bins[HOT_BINS];
    int stride = *stride_p;
    bool cls = use_class(stride, ws_size);
    int nc = num_classes(stride);
    const bool hot_ok = (stride >= 1) && (stride <= 2);
    const int tid = threadIdx.x;
    for (int i = tid; i < HOT_BINS; i += SH_THREADS) lds_bins[i] = 0.0f;
    __syncthreads();
    const int gsz = gridDim.x * SH_THREADS;
    for (int i = blockIdx.x * SH_THREADS + tid; i < n; i += gsz) {
        int t = ticks[i];
        int x = xs[i];
        int y = ys[i];
        float v = vals[i];
        if (hot_ok && cls && x >= KW - 1 && y >= KH - 1) {
            int c4 = ((x - (KW - 1)) % stride) * 2 + ((y - (KH - 1)) % stride);
            atomicAdd(&lds_bins[t * 4 + c4], v);           // ds_add_f32
        } else {
            scatter_event_cold(t, x, y, v, stride, cls, nc, ws);
        }
    }
    __syncthreads();
    float* slab = (float*)((char*)ws + HOT_OFF_B) + (size_t)blockIdx.x * HOT_BINS;
    for (int i = tid; i < HOT_BINS; i += SH_THREADS) slab[i] = lds_bins[i];
}

__global__ void reduce_hot(const int* __restrict__ stride_p, float* ws,
                           unsigned long long ws_size, int nbh) {
    int stride = *stride_p;
    if (!use_class(stride, ws_size) || stride < 1 || stride > 2) return;
    int i = blockIdx.x * blockDim.x + threadIdx.x;
    if (i >= HOT_BINS) return;
    int t  = i >> 2;
    int c4 = i & 3;
    int cxr = c4 >> 1, cyr = c4 & 1;
    if (cxr >= stride || cyr >= stride) return;
    const float* slab0 = (const float*)((const char*)ws + HOT_OFF_B);
    float s = 0.0f;
    for (int b = 0; b < nbh; ++b) s += slab0[(size_t)b * HOT_BINS + i];
    int nc = num_classes(stride);
    float* bins = (float*)((char*)ws + BINS_OFF_B);
    bins[((long long)t * nc + (KW - 1 + cxr)) * nc + (KH - 1 + cyr)] += s;
}

__global__ void combine_kernel(const int* __restrict__ stride_p, float* ws,
                               unsigned long long ws_size) {
    int stride = *stride_p;
    if (!use_class(stride, ws_size)) return;
    int nc = num_classes(stride);
    const float* bins = (const float*)((const char*)ws + BINS_OFF_B);
    int i = blockIdx.x * blockDim.x + threadIdx.x;
    if (i >= BUF_ELEMS) return;
    int tap = i / TICKS;
    int t   = i % TICKS;
    int ky = tap / KW, kx = tap % KW;
    float s = 0.0f;
    for (int cx = kx; cx < nc; cx += stride)
        for (int cy = ky; cy < nc; cy += stride)
            s += bins[((long long)t * nc + cx) * nc + cy];
    ws[tap * TICKS + t] = s;
}

// P^T[c][t] = sum_tap W[c,tap] * buf[tap, t-1]   (1-tick delay; P^T[c][0]=0)
__global__ void matmul_kernel(const float* __restrict__ W, float* ws) {
    int gid = blockIdx.x * blockDim.x + threadIdx.x;
    if (gid >= P_ELEMS) return;
    int c = gid / TICKS;
    int t = gid - c * TICKS;
    const float* buf = ws;
    float* PT = (float*)((char*)ws + P_OFF_B);
    float acc = 0.0f;
    if (t > 0) {
        const float* wrow = W + c * NTAPS;
        const float* bcol = buf + (t - 1);
        #pragma unroll
        for (int tap = 0; tap < NTAPS; ++tap)
            acc += wrow[tap] * bcol[tap * TICKS];
    }
    PT[gid] = acc;
}

// sim v3: r7 showed VGPR=68 -> compiler sank the "prefetch" loads to point-of-use
// (500 exposed ~200cy L2 loads = the 57.6us).  Countermeasures:
//  - sched_barrier(0) after each prefetch-issue block: loads cannot move down.
//  - KEEP4 empty-asm "+v" pin on every buffered float4 just before consumption:
//    values MUST be in VGPRs there, a full chunk (~1400cy) after issue.
// SCH=40 -> every chunk start %4==0: single flush phase, 10 float4 per buffer.
// Per-tick arithmetic frozen (textually identical to r6/r7-passing versions).
#define SCH 40
#define SF4 (SCH / 4)          // 10 float4 per chunk
#define NCH (TICKS / SCH)      // 25 chunks

#define KEEP4(b) asm volatile("" : "+v"((b).x), "+v"((b).y), "+v"((b).z), "+v"((b).w))

#define PREFETCH(BUF, T0)                                                  \
    {                                                                      \
        const float4* s_ = base4 + ((T0) >> 2);                            \
        _Pragma("unroll")                                                  \
        for (int j = 0; j < SF4; ++j) BUF[j] = s_[j];                      \
    }                                                                      \
    __builtin_amdgcn_sched_barrier(0);

#define PIN(BUF)                                                           \
    _Pragma("unroll")                                                      \
    for (int j = 0; j < SF4; ++j) KEEP4(BUF[j]);

#define RUN_CHUNK40(BUF, T0)                                               \
    _Pragma("unroll")                                                      \
    for (int tt = 0; tt < SCH; ++tt) {                                     \
        const float4 pv_ = BUF[tt >> 2];                                   \
        float p = ((tt & 3) == 0 ? pv_.x : (tt & 3) == 1 ? pv_.y           \
                  : (tt & 3) == 2 ? pv_.z : pv_.w);                        \
        ssum = ssum * DECAY + p;                                           \
        float I = 350.0f + ssum;                                           \
        float q = 1.2f * (v - (-75.0f));                                   \
        q = q * (v - (-45.0f));                                            \
        v = v + (q - u + I) * DTC;                                         \
        u = u + 0.01f * (5.0f * (v - (-75.0f)) - u) * 0.001f;              \
        float spk;                                                         \
        if (v >= 50.0f) { spk = 1.0f; v = -56.0f; u = u + 130.0f; }        \
        else            { spk = 0.0f; }                                    \
        o_s[tt & 3] = spk;                                                 \
        o_v[tt & 3] = v;                                                   \
        if ((tt & 3) == 3) {                                               \
            const int tb = (T0) + tt - 3;  /* tb%4==0: 16B aligned */      \
            *(float4*)(out + (size_t)c * TICKS + tb) =                     \
                make_float4(o_s[0], o_s[1], o_s[2], o_s[3]);               \
            *(float4*)(out + (size_t)(OUT_CH * TICKS) + (size_t)c * TICKS + tb) = \
                make_float4(o_v[0], o_v[1], o_v[2], o_v[3]);               \
        }                                                                  \
    }

__global__ void __launch_bounds__(OUT_CH) sim_kernel(const float* __restrict__ ws_c,
                                                     float* __restrict__ out) {
    const float* PT = (const float*)((const char*)ws_c + P_OFF_B);
    const int c = threadIdx.x;
    const float4* base4 = (const float4*)(PT + (size_t)c * TICKS);  // 4000c B: 16B-aligned
    const float DECAY = (float)(1.0 - 0.001 / 0.01);
    const float DTC   = (float)(0.001 / 150.0);
    float v = -75.0f, u = 0.0f, ssum = 0.0f;
    float o_s[4], o_v[4];
    float4 bufA[SF4], bufB[SF4];

    PREFETCH(bufA, 0)                       // prologue (one-time exposed latency)
    for (int kp = 0; kp < (NCH - 1) / 2; ++kp) {       // 12 pairs: chunks 0..23
        const int t0 = kp * 2 * SCH;
        PREFETCH(bufB, t0 + SCH)
        PIN(bufA)
        RUN_CHUNK40(bufA, t0)
        PREFETCH(bufA, t0 + 2 * SCH)        // chunks 2,4,...,24
        PIN(bufB)
        RUN_CHUNK40(bufB, t0 + SCH)
    }
    PIN(bufA)
    RUN_CHUNK40(bufA, (NCH - 1) * SCH)      // chunk 24: ticks 960..999
}

extern "C" void kernel_launch(void* const* d_in, const int* in_sizes, int n_in,
                              void* d_out, int out_size, void* d_ws, size_t ws_size,
                              hipStream_t stream) {
    const int*   ticks   = (const int*)d_in[0];
    const int*   xs      = (const int*)d_in[1];
    const int*   ys      = (const int*)d_in[2];
    const float* vals    = (const float*)d_in[3];
    const float* W       = (const float*)d_in[4];
    const int*   stridep = (const int*)d_in[5];
    float* ws  = (float*)d_ws;
    float* out = (float*)d_out;
    int n = in_sizes[0];
    unsigned long long wsz = (unsigned long long)ws_size;

    int nbh = 0;
    if (ws_size >= (size_t)HOT_OFF_B + 8 * (size_t)HOT_SLAB_B) {
        size_t fit = (ws_size - HOT_OFF_B) / HOT_SLAB_B;
        nbh = fit < NBH_MAX ? (int)fit : NBH_MAX;
    }

    zero_kernel<<<1024, 256, 0, stream>>>(ws, stridep, wsz);
    if (nbh > 0) {
        scatter_hot<<<nbh, SH_THREADS, 0, stream>>>(ticks, xs, ys, vals,
                                                    stridep, ws, wsz, n);
        reduce_hot<<<(HOT_BINS + 255) / 256, 256, 0, stream>>>(stridep, ws, wsz, nbh);
    } else {
        scatter_kernel<<<(n + 255) / 256, 256, 0, stream>>>(ticks, xs, ys, vals,
                                                            stridep, ws, wsz, n);
    }
    combine_kernel<<<(BUF_ELEMS + 255) / 256, 256, 0, stream>>>(stridep, ws, wsz);
    matmul_kernel<<<(P_ELEMS + 255) / 256, 256, 0, stream>>>(W, ws);
    sim_kernel<<<1, OUT_CH, 0, stream>>>(ws, out);
}

// Round 13
// 160.175 us; speedup vs baseline: 1.3517x; 1.3517x over previous
//
#include <hip/hip_runtime.h>
#include <cstdint>

#define TICKS   1000
#define KH      7
#define KW      7
#define NTAPS   49
#define OUT_CH  128

#define BUF_ELEMS   (NTAPS * TICKS)      // 49000 floats at ws[0]
#define P_OFF_B     196608               // byte offset of P^T[c*1000+t] (128000 floats)
#define P_ELEMS     (OUT_CH * TICKS)
#define BINS_OFF_B  708608               // byte offset of class bins
#define HOT_OFF_B   1757184              // byte offset of per-block hot slabs
#define HOT_BINS    4000                 // 1000 ticks x 4 hot classes
#define HOT_SLAB_B  (HOT_BINS * 4)       // 16 KB per block
#define NBH_MAX     256
#define SH_THREADS  1024                 // r10: 256->1024 (r7 ran 1 wave/SIMD: latency-starved)
#define RED_GROUP   16                   // r12: slabs per reduce-thread (was nbh=256 serial)

// x-classes: x<6 -> x exactly; x>=6 -> 6 + (x-6)%stride.  Validity of tap kx for
// class cx is (cx>=kx) && ((cx-kx)%stride==0) — exact for x<6; for x>=6, cx>=6>=kx
// always, and (x-kx) ≡ (cx-kx) (mod stride) since x ≡ cx (mod stride).
static __device__ __forceinline__ int num_classes(int stride) {
    int n = (KW - 1) + stride;
    return n > 128 ? 128 : n;
}

static __device__ __forceinline__ bool use_class(int stride, unsigned long long ws_size) {
    if (stride < 1) return false;
    long long nc = num_classes(stride);
    long long bytes = (long long)TICKS * nc * nc * 4;
    return (long long)BINS_OFF_B + bytes <= (long long)ws_size;
}

static __device__ __forceinline__ void scatter_event_cold(
        int t, int x, int y, float v, int stride, bool cls, int nc, float* ws) {
    float* buf  = ws;
    float* bins = (float*)((char*)ws + BINS_OFF_B);
    if (cls) {
        int cx = (x < KW - 1) ? x : (KW - 1) + (x - (KW - 1)) % stride;
        int cy = (y < KH - 1) ? y : (KH - 1) + (y - (KH - 1)) % stride;
        unsafeAtomicAdd(&bins[((long long)t * nc + cx) * nc + cy], v);
    } else {
        for (int ky = 0; ky < KH; ++ky) {
            int oy = y - ky;
            if (oy < 0 || (oy % stride) != 0) continue;
            for (int kx = 0; kx < KW; ++kx) {
                int ox = x - kx;
                if (ox < 0 || (ox % stride) != 0) continue;
                unsafeAtomicAdd(&buf[(ky * KW + kx) * TICKS + t], v);
            }
        }
    }
}

__global__ void zero_kernel(float* ws, const int* __restrict__ stride_p,
                            unsigned long long ws_size) {
    int stride = *stride_p;
    long long nbins = 0;
    if (use_class(stride, ws_size)) {
        long long nc = num_classes(stride);
        nbins = (long long)TICKS * nc * nc;
    }
    float* bins = (float*)((char*)ws + BINS_OFF_B);
    long long gid = (long long)blockIdx.x * blockDim.x + threadIdx.x;
    long long gsz = (long long)gridDim.x * blockDim.x;
    for (long long i = gid; i < BUF_ELEMS; i += gsz) ws[i] = 0.0f;
    for (long long i = gid; i < nbins; i += gsz) bins[i] = 0.0f;
}

// legacy path (ws too small for hot slabs): 1 global atomic / event
__global__ void scatter_kernel(const int* __restrict__ ticks, const int* __restrict__ xs,
                               const int* __restrict__ ys, const float* __restrict__ vals,
                               const int* __restrict__ stride_p, float* ws,
                               unsigned long long ws_size, int n) {
    int stride = *stride_p;
    bool cls = use_class(stride, ws_size);
    int nc = num_classes(stride);
    int gid = blockIdx.x * blockDim.x + threadIdx.x;
    if (gid >= n) return;
    scatter_event_cold(ticks[gid], xs[gid], ys[gid], vals[gid], stride, cls, nc, ws);
}

// Hot path: ~91% of events (stride<=2: x>=6 && y>=6) collapse onto <=4 classes
// per tick -> per-block LDS histogram, coalesced flush to private slab.
__global__ void __launch_bounds__(SH_THREADS) scatter_hot(
        const int* __restrict__ ticks, const int* __restrict__ xs,
        const int* __restrict__ ys, const float* __restrict__ vals,
        const int* __restrict__ stride_p, float* ws,
        unsigned long long ws_size, int n) {
    __shared__ float lds_bins[HOT_BINS];
    int stride = *stride_p;
    bool cls = use_class(stride, ws_size);
    int nc = num_classes(stride);
    const bool hot_ok = (stride >= 1) && (stride <= 2);
    const int tid = threadIdx.x;
    for (int i = tid; i < HOT_BINS; i += SH_THREADS) lds_bins[i] = 0.0f;
    __syncthreads();
    const int gsz = gridDim.x * SH_THREADS;
    for (int i = blockIdx.x * SH_THREADS + tid; i < n; i += gsz) {
        int t = ticks[i];
        int x = xs[i];
        int y = ys[i];
        float v = vals[i];
        if (hot_ok && cls && x >= KW - 1 && y >= KH - 1) {
            int c4 = ((x - (KW - 1)) % stride) * 2 + ((y - (KH - 1)) % stride);
            atomicAdd(&lds_bins[t * 4 + c4], v);           // ds_add_f32
        } else {
            scatter_event_cold(t, x, y, v, stride, cls, nc, ws);
        }
    }
    __syncthreads();
    float* slab = (float*)((char*)ws + HOT_OFF_B) + (size_t)blockIdx.x * HOT_BINS;
    for (int i = tid; i < HOT_BINS; i += SH_THREADS) slab[i] = lds_bins[i];
}

// r12: parallel over (bin, slab-group).  r7/r12's version was 16 blocks with a
// 256-deep serial sum per thread (Occupancy 0.63%, 64.8us, 33GB/s — latency-
// bound).  Now thread (g,i) sums RED_GROUP slabs for bin i (coalesced in i) and
// atomically accumulates into bins.  Sums are integer-valued counts -> exact in
// any order; cold-path atomics finished in the previous dispatch.
__global__ void reduce_hot(const int* __restrict__ stride_p, float* ws,
                           unsigned long long ws_size, int nbh, int ngroups) {
    int stride = *stride_p;
    if (!use_class(stride, ws_size) || stride < 1 || stride > 2) return;
    int id = blockIdx.x * blockDim.x + threadIdx.x;
    if (id >= HOT_BINS * ngroups) return;
    int g = id / HOT_BINS;
    int i = id - g * HOT_BINS;            // consecutive id -> consecutive i: coalesced
    int t  = i >> 2;
    int c4 = i & 3;
    int cxr = c4 >> 1, cyr = c4 & 1;
    if (cxr >= stride || cyr >= stride) return;   // unused classes for stride 1
    const float* slab0 = (const float*)((const char*)ws + HOT_OFF_B);
    int b0 = g * RED_GROUP;
    int b1 = b0 + RED_GROUP; if (b1 > nbh) b1 = nbh;
    float s = 0.0f;
    for (int b = b0; b < b1; ++b) s += slab0[(size_t)b * HOT_BINS + i];
    int nc = num_classes(stride);
    float* bins = (float*)((char*)ws + BINS_OFF_B);
    unsafeAtomicAdd(&bins[((long long)t * nc + (KW - 1 + cxr)) * nc + (KH - 1 + cyr)], s);
}

__global__ void combine_kernel(const int* __restrict__ stride_p, float* ws,
                               unsigned long long ws_size) {
    int stride = *stride_p;
    if (!use_class(stride, ws_size)) return;
    int nc = num_classes(stride);
    const float* bins = (const float*)((const char*)ws + BINS_OFF_B);
    int i = blockIdx.x * blockDim.x + threadIdx.x;
    if (i >= BUF_ELEMS) return;
    int tap = i / TICKS;
    int t   = i % TICKS;
    int ky = tap / KW, kx = tap % KW;
    float s = 0.0f;
    for (int cx = kx; cx < nc; cx += stride)
        for (int cy = ky; cy < nc; cy += stride)
            s += bins[((long long)t * nc + cx) * nc + cy];
    ws[tap * TICKS + t] = s;
}

// P^T[c][t] = sum_tap W[c,tap] * buf[tap, t-1]   (1-tick delay; P^T[c][0]=0)
__global__ void matmul_kernel(const float* __restrict__ W, float* ws) {
    int gid = blockIdx.x * blockDim.x + threadIdx.x;
    if (gid >= P_ELEMS) return;
    int c = gid / TICKS;
    int t = gid - c * TICKS;
    const float* buf = ws;
    float* PT = (float*)((char*)ws + P_OFF_B);
    float acc = 0.0f;
    if (t > 0) {
        const float* wrow = W + c * NTAPS;
        const float* bcol = buf + (t - 1);
        #pragma unroll
        for (int tap = 0; tap < NTAPS; ++tap)
            acc += wrow[tap] * bcol[tap * TICKS];
    }
    PT[gid] = acc;
}

// sim v3 (unchanged, still under test): sched_barrier-pinned prefetch + KEEP4
// register pins; per-tick arithmetic frozen.
#define SCH 40
#define SF4 (SCH / 4)          // 10 float4 per chunk
#define NCH (TICKS / SCH)      // 25 chunks

#define KEEP4(b) asm volatile("" : "+v"((b).x), "+v"((b).y), "+v"((b).z), "+v"((b).w))

#define PREFETCH(BUF, T0)                                                  \
    {                                                                      \
        const float4* s_ = base4 + ((T0) >> 2);                            \
        _Pragma("unroll")                                                  \
        for (int j = 0; j < SF4; ++j) BUF[j] = s_[j];                      \
    }                                                                      \
    __builtin_amdgcn_sched_barrier(0);

#define PIN(BUF)                                                           \
    _Pragma("unroll")                                                      \
    for (int j = 0; j < SF4; ++j) KEEP4(BUF[j]);

#define RUN_CHUNK40(BUF, T0)                                               \
    _Pragma("unroll")                                                      \
    for (int tt = 0; tt < SCH; ++tt) {                                     \
        const float4 pv_ = BUF[tt >> 2];                                   \
        float p = ((tt & 3) == 0 ? pv_.x : (tt & 3) == 1 ? pv_.y           \
                  : (tt & 3) == 2 ? pv_.z : pv_.w);                        \
        ssum = ssum * DECAY + p;                                           \
        float I = 350.0f + ssum;                                           \
        float q = 1.2f * (v - (-75.0f));                                   \
        q = q * (v - (-45.0f));                                            \
        v = v + (q - u + I) * DTC;                                         \
        u = u + 0.01f * (5.0f * (v - (-75.0f)) - u) * 0.001f;              \
        float spk;                                                         \
        if (v >= 50.0f) { spk = 1.0f; v = -56.0f; u = u + 130.0f; }        \
        else            { spk = 0.0f; }                                    \
        o_s[tt & 3] = spk;                                                 \
        o_v[tt & 3] = v;                                                   \
        if ((tt & 3) == 3) {                                               \
            const int tb = (T0) + tt - 3;  /* tb%4==0: 16B aligned */      \
            *(float4*)(out + (size_t)c * TICKS + tb) =                     \
                make_float4(o_s[0], o_s[1], o_s[2], o_s[3]);               \
            *(float4*)(out + (size_t)(OUT_CH * TICKS) + (size_t)c * TICKS + tb) = \
                make_float4(o_v[0], o_v[1], o_v[2], o_v[3]);               \
        }                                                                  \
    }

__global__ void __launch_bounds__(OUT_CH) sim_kernel(const float* __restrict__ ws_c,
                                                     float* __restrict__ out) {
    const float* PT = (const float*)((const char*)ws_c + P_OFF_B);
    const int c = threadIdx.x;
    const float4* base4 = (const float4*)(PT + (size_t)c * TICKS);  // 4000c B: 16B-aligned
    const float DECAY = (float)(1.0 - 0.001 / 0.01);
    const float DTC   = (float)(0.001 / 150.0);
    float v = -75.0f, u = 0.0f, ssum = 0.0f;
    float o_s[4], o_v[4];
    float4 bufA[SF4], bufB[SF4];

    PREFETCH(bufA, 0)                       // prologue (one-time exposed latency)
    for (int kp = 0; kp < (NCH - 1) / 2; ++kp) {       // 12 pairs: chunks 0..23
        const int t0 = kp * 2 * SCH;
        PREFETCH(bufB, t0 + SCH)
        PIN(bufA)
        RUN_CHUNK40(bufA, t0)
        PREFETCH(bufA, t0 + 2 * SCH)        // chunks 2,4,...,24
        PIN(bufB)
        RUN_CHUNK40(bufB, t0 + SCH)
    }
    PIN(bufA)
    RUN_CHUNK40(bufA, (NCH - 1) * SCH)      // chunk 24: ticks 960..999
}

extern "C" void kernel_launch(void* const* d_in, const int* in_sizes, int n_in,
                              void* d_out, int out_size, void* d_ws, size_t ws_size,
                              hipStream_t stream) {
    const int*   ticks   = (const int*)d_in[0];
    const int*   xs      = (const int*)d_in[1];
    const int*   ys      = (const int*)d_in[2];
    const float* vals    = (const float*)d_in[3];
    const float* W       = (const float*)d_in[4];
    const int*   stridep = (const int*)d_in[5];
    float* ws  = (float*)d_ws;
    float* out = (float*)d_out;
    int n = in_sizes[0];
    unsigned long long wsz = (unsigned long long)ws_size;

    int nbh = 0;
    if (ws_size >= (size_t)HOT_OFF_B + 8 * (size_t)HOT_SLAB_B) {
        size_t fit = (ws_size - HOT_OFF_B) / HOT_SLAB_B;
        nbh = fit < NBH_MAX ? (int)fit : NBH_MAX;
    }

    zero_kernel<<<1024, 256, 0, stream>>>(ws, stridep, wsz);
    if (nbh > 0) {
        scatter_hot<<<nbh, SH_THREADS, 0, stream>>>(ticks, xs, ys, vals,
                                                    stridep, ws, wsz, n);
        int ngroups = (nbh + RED_GROUP - 1) / RED_GROUP;
        int rthreads = HOT_BINS * ngroups;
        reduce_hot<<<(rthreads + 255) / 256, 256, 0, stream>>>(stridep, ws, wsz,
                                                               nbh, ngroups);
    } else {
        scatter_kernel<<<(n + 255) / 256, 256, 0, stream>>>(ticks, xs, ys, vals,
                                                            stridep, ws, wsz, n);
    }
    combine_kernel<<<(BUF_ELEMS + 255) / 256, 256, 0, stream>>>(stridep, ws, wsz);
    matmul_kernel<<<(P_ELEMS + 255) / 256, 256, 0, stream>>>(W, ws);
    sim_kernel<<<1, OUT_CH, 0, stream>>>(ws, out);
}

// Round 14
// 140.663 us; speedup vs baseline: 1.5392x; 1.1387x over previous
//
#include <hip/hip_runtime.h>
#include <cstdint>

#define TICKS   1000
#define KH      7
#define KW      7
#define NTAPS   49
#define OUT_CH  128

#define BUF_ELEMS   (NTAPS * TICKS)      // 49000 floats at ws[0]
#define P_OFF_B     196608               // byte offset of P^T[c*1000+t] (128000 floats)
#define P_ELEMS     (OUT_CH * TICKS)
#define BINS_OFF_B  708608               // byte offset of class bins
#define HOT_OFF_B   1757184              // byte offset of per-block hot slabs
#define HOT_BINS    4000                 // 1000 ticks x 4 hot classes
#define HOT_SLAB_B  (HOT_BINS * 4)       // 16 KB per block
#define NBH_MAX     256
#define SH_THREADS  1024                 // r10: 16 waves/CU (r7's 256thr was latency-starved)
#define RED_GROUP   16                   // r12: slabs per reduce-thread

typedef float f32x4 __attribute__((ext_vector_type(4)));

// x-classes: x<6 -> x exactly; x>=6 -> 6 + (x-6)%stride.  Validity of tap kx for
// class cx is (cx>=kx) && ((cx-kx)%stride==0) — exact for x<6; for x>=6, cx>=6>=kx
// always, and (x-kx) ≡ (cx-kx) (mod stride) since x ≡ cx (mod stride).
static __device__ __forceinline__ int num_classes(int stride) {
    int n = (KW - 1) + stride;
    return n > 128 ? 128 : n;
}

static __device__ __forceinline__ bool use_class(int stride, unsigned long long ws_size) {
    if (stride < 1) return false;
    long long nc = num_classes(stride);
    long long bytes = (long long)TICKS * nc * nc * 4;
    return (long long)BINS_OFF_B + bytes <= (long long)ws_size;
}

static __device__ __forceinline__ void scatter_event_cold(
        int t, int x, int y, float v, int stride, bool cls, int nc, float* ws) {
    float* buf  = ws;
    float* bins = (float*)((char*)ws + BINS_OFF_B);
    if (cls) {
        int cx = (x < KW - 1) ? x : (KW - 1) + (x - (KW - 1)) % stride;
        int cy = (y < KH - 1) ? y : (KH - 1) + (y - (KH - 1)) % stride;
        unsafeAtomicAdd(&bins[((long long)t * nc + cx) * nc + cy], v);
    } else {
        for (int ky = 0; ky < KH; ++ky) {
            int oy = y - ky;
            if (oy < 0 || (oy % stride) != 0) continue;
            for (int kx = 0; kx < KW; ++kx) {
                int ox = x - kx;
                if (ox < 0 || (ox % stride) != 0) continue;
                unsafeAtomicAdd(&buf[(ky * KW + kx) * TICKS + t], v);
            }
        }
    }
}

__global__ void zero_kernel(float* ws, const int* __restrict__ stride_p,
                            unsigned long long ws_size) {
    int stride = *stride_p;
    long long nbins = 0;
    if (use_class(stride, ws_size)) {
        long long nc = num_classes(stride);
        nbins = (long long)TICKS * nc * nc;
    }
    float* bins = (float*)((char*)ws + BINS_OFF_B);
    long long gid = (long long)blockIdx.x * blockDim.x + threadIdx.x;
    long long gsz = (long long)gridDim.x * blockDim.x;
    for (long long i = gid; i < BUF_ELEMS; i += gsz) ws[i] = 0.0f;
    for (long long i = gid; i < nbins; i += gsz) bins[i] = 0.0f;
}

// legacy path (ws too small for hot slabs): 1 global atomic / event
__global__ void scatter_kernel(const int* __restrict__ ticks, const int* __restrict__ xs,
                               const int* __restrict__ ys, const float* __restrict__ vals,
                               const int* __restrict__ stride_p, float* ws,
                               unsigned long long ws_size, int n) {
    int stride = *stride_p;
    bool cls = use_class(stride, ws_size);
    int nc = num_classes(stride);
    int gid = blockIdx.x * blockDim.x + threadIdx.x;
    if (gid >= n) return;
    scatter_event_cold(ticks[gid], xs[gid], ys[gid], vals[gid], stride, cls, nc, ws);
}

// Hot path: ~91% of events (stride<=2: x>=6 && y>=6) collapse onto <=4 classes
// per tick -> per-block LDS histogram, coalesced flush to private slab.
__global__ void __launch_bounds__(SH_THREADS) scatter_hot(
        const int* __restrict__ ticks, const int* __restrict__ xs,
        const int* __restrict__ ys, const float* __restrict__ vals,
        const int* __restrict__ stride_p, float* ws,
        unsigned long long ws_size, int n) {
    __shared__ float lds_bins[HOT_BINS];
    int stride = *stride_p;
    bool cls = use_class(stride, ws_size);
    int nc = num_classes(stride);
    const bool hot_ok = (stride >= 1) && (stride <= 2);
    const int tid = threadIdx.x;
    for (int i = tid; i < HOT_BINS; i += SH_THREADS) lds_bins[i] = 0.0f;
    __syncthreads();
    const int gsz = gridDim.x * SH_THREADS;
    for (int i = blockIdx.x * SH_THREADS + tid; i < n; i += gsz) {
        int t = ticks[i];
        int x = xs[i];
        int y = ys[i];
        float v = vals[i];
        if (hot_ok && cls && x >= KW - 1 && y >= KH - 1) {
            int c4 = ((x - (KW - 1)) % stride) * 2 + ((y - (KH - 1)) % stride);
            atomicAdd(&lds_bins[t * 4 + c4], v);           // ds_add_f32
        } else {
            scatter_event_cold(t, x, y, v, stride, cls, nc, ws);
        }
    }
    __syncthreads();
    float* slab = (float*)((char*)ws + HOT_OFF_B) + (size_t)blockIdx.x * HOT_BINS;
    for (int i = tid; i < HOT_BINS; i += SH_THREADS) slab[i] = lds_bins[i];
}

// r12: parallel over (bin, slab-group); counts are integer-valued -> exact sums.
__global__ void reduce_hot(const int* __restrict__ stride_p, float* ws,
                           unsigned long long ws_size, int nbh, int ngroups) {
    int stride = *stride_p;
    if (!use_class(stride, ws_size) || stride < 1 || stride > 2) return;
    int id = blockIdx.x * blockDim.x + threadIdx.x;
    if (id >= HOT_BINS * ngroups) return;
    int g = id / HOT_BINS;
    int i = id - g * HOT_BINS;            // consecutive id -> consecutive i: coalesced
    int t  = i >> 2;
    int c4 = i & 3;
    int cxr = c4 >> 1, cyr = c4 & 1;
    if (cxr >= stride || cyr >= stride) return;
    const float* slab0 = (const float*)((const char*)ws + HOT_OFF_B);
    int b0 = g * RED_GROUP;
    int b1 = b0 + RED_GROUP; if (b1 > nbh) b1 = nbh;
    float s = 0.0f;
    for (int b = b0; b < b1; ++b) s += slab0[(size_t)b * HOT_BINS + i];
    int nc = num_classes(stride);
    float* bins = (float*)((char*)ws + BINS_OFF_B);
    unsafeAtomicAdd(&bins[((long long)t * nc + (KW - 1 + cxr)) * nc + (KH - 1 + cyr)], s);
}

__global__ void combine_kernel(const int* __restrict__ stride_p, float* ws,
                               unsigned long long ws_size) {
    int stride = *stride_p;
    if (!use_class(stride, ws_size)) return;
    int nc = num_classes(stride);
    const float* bins = (const float*)((const char*)ws + BINS_OFF_B);
    int i = blockIdx.x * blockDim.x + threadIdx.x;
    if (i >= BUF_ELEMS) return;
    int tap = i / TICKS;
    int t   = i % TICKS;
    int ky = tap / KW, kx = tap % KW;
    float s = 0.0f;
    for (int cx = kx; cx < nc; cx += stride)
        for (int cy = ky; cy < nc; cy += stride)
            s += bins[((long long)t * nc + cx) * nc + cy];
    ws[tap * TICKS + t] = s;
}

// P^T[c][t] = sum_tap W[c,tap] * buf[tap, t-1]   (1-tick delay; P^T[c][0]=0)
__global__ void matmul_kernel(const float* __restrict__ W, float* ws) {
    int gid = blockIdx.x * blockDim.x + threadIdx.x;
    if (gid >= P_ELEMS) return;
    int c = gid / TICKS;
    int t = gid - c * TICKS;
    const float* buf = ws;
    float* PT = (float*)((char*)ws + P_OFF_B);
    float acc = 0.0f;
    if (t > 0) {
        const float* wrow = W + c * NTAPS;
        const float* bcol = buf + (t - 1);
        #pragma unroll
        for (int tap = 0; tap < NTAPS; ++tap)
            acc += wrow[tap] * bcol[tap * TICKS];
    }
    PT[gid] = acc;
}

// sim v4: r13 verdict — VGPR=76 proves KEEP4/sched_barrier pins were defeated;
// the compiler re-sank the C++ loads (57.6->64.3us).  Escalation (T4 pattern):
//  - loads ARE inline asm (global_load_dwordx4, base VGPR-pair + offset:16j):
//    un-sinkable, un-deletable;
//  - counted s_waitcnt vmcnt(N) (never 0 in loop): after issuing next chunk's
//    10 loads and running the current chunk (20 C++ stores, boxed by "memory"
//    clobbers so the in-window store count is exact), vmcnt(20) retires exactly
//    the prefetched loads (in-order VMEM retirement);
//  - sched_barrier(0) + volatile "+v" pin after each wait (rule #18: hipcc
//    hoists register-only math past inline-asm waitcnt without a data fence).
//  - grid 2x64 (was 1x128): waves are independent; 2 CUs -> halves per-CU
//    scattered-store TA pressure, doubles load BW.
// Per-tick arithmetic frozen (textually identical to all passing versions).
#define SCH 40
#define SF4 (SCH / 4)          // 10 float4 per chunk
#define NCH (TICKS / SCH)      // 25 chunks

#define ASM_LOAD10(BUF, T0)                                                     \
    {                                                                           \
        const f32x4* p_ = base4 + ((T0) >> 2);                                  \
        asm volatile("global_load_dwordx4 %0, %1, off offset:0"   : "=v"(BUF[0]) : "v"(p_) : "memory"); \
        asm volatile("global_load_dwordx4 %0, %1, off offset:16"  : "=v"(BUF[1]) : "v"(p_) : "memory"); \
        asm volatile("global_load_dwordx4 %0, %1, off offset:32"  : "=v"(BUF[2]) : "v"(p_) : "memory"); \
        asm volatile("global_load_dwordx4 %0, %1, off offset:48"  : "=v"(BUF[3]) : "v"(p_) : "memory"); \
        asm volatile("global_load_dwordx4 %0, %1, off offset:64"  : "=v"(BUF[4]) : "v"(p_) : "memory"); \
        asm volatile("global_load_dwordx4 %0, %1, off offset:80"  : "=v"(BUF[5]) : "v"(p_) : "memory"); \
        asm volatile("global_load_dwordx4 %0, %1, off offset:96"  : "=v"(BUF[6]) : "v"(p_) : "memory"); \
        asm volatile("global_load_dwordx4 %0, %1, off offset:112" : "=v"(BUF[7]) : "v"(p_) : "memory"); \
        asm volatile("global_load_dwordx4 %0, %1, off offset:128" : "=v"(BUF[8]) : "v"(p_) : "memory"); \
        asm volatile("global_load_dwordx4 %0, %1, off offset:144" : "=v"(BUF[9]) : "v"(p_) : "memory"); \
    }

// wait until the 10 loads older than the newest N VMEM ops have retired, then
// fence (sched_barrier) and data-pin the buffer so no use can be hoisted.
#define WAITPIN(N, BUF)                                                         \
    asm volatile("s_waitcnt vmcnt(" #N ")" ::: "memory");                       \
    __builtin_amdgcn_sched_barrier(0);                                          \
    asm volatile("" : "+v"(BUF[0]), "+v"(BUF[1]), "+v"(BUF[2]), "+v"(BUF[3]),   \
                      "+v"(BUF[4]), "+v"(BUF[5]), "+v"(BUF[6]), "+v"(BUF[7]),   \
                      "+v"(BUF[8]), "+v"(BUF[9]));

#define RUN_CHUNK40(BUF, T0)                                               \
    _Pragma("unroll")                                                      \
    for (int tt = 0; tt < SCH; ++tt) {                                     \
        float p = BUF[tt >> 2][tt & 3];                                    \
        ssum = ssum * DECAY + p;                                           \
        float I = 350.0f + ssum;                                           \
        float q = 1.2f * (v - (-75.0f));                                   \
        q = q * (v - (-45.0f));                                            \
        v = v + (q - u + I) * DTC;                                         \
        u = u + 0.01f * (5.0f * (v - (-75.0f)) - u) * 0.001f;              \
        float spk;                                                         \
        if (v >= 50.0f) { spk = 1.0f; v = -56.0f; u = u + 130.0f; }        \
        else            { spk = 0.0f; }                                    \
        o_s[tt & 3] = spk;                                                 \
        o_v[tt & 3] = v;                                                   \
        if ((tt & 3) == 3) {                                               \
            const int tb = (T0) + tt - 3;  /* tb%4==0: 16B aligned */      \
            *(float4*)(out + (size_t)c * TICKS + tb) =                     \
                make_float4(o_s[0], o_s[1], o_s[2], o_s[3]);               \
            *(float4*)(out + (size_t)(OUT_CH * TICKS) + (size_t)c * TICKS + tb) = \
                make_float4(o_v[0], o_v[1], o_v[2], o_v[3]);               \
        }                                                                  \
    }

__global__ void __launch_bounds__(64) sim_kernel(const float* __restrict__ ws_c,
                                                 float* __restrict__ out) {
    const float* PT = (const float*)((const char*)ws_c + P_OFF_B);
    const int c = blockIdx.x * 64 + threadIdx.x;        // 2 blocks x 64 neurons
    const f32x4* base4 = (const f32x4*)(PT + (size_t)c * TICKS);  // 16B-aligned
    const float DECAY = (float)(1.0 - 0.001 / 0.01);
    const float DTC   = (float)(0.001 / 150.0);
    float v = -75.0f, u = 0.0f, ssum = 0.0f;
    float o_s[4], o_v[4];
    f32x4 bufA[SF4], bufB[SF4];

    ASM_LOAD10(bufA, 0)
    WAITPIN(0, bufA)                       // prologue: one-time full drain
    for (int kp = 0; kp < (NCH - 1) / 2; ++kp) {        // 12 pairs: chunks 0..23
        const int t0 = kp * 2 * SCH;
        ASM_LOAD10(bufB, t0 + SCH)         // in flight during run(A)
        RUN_CHUNK40(bufA, t0)              // 20 stores
        WAITPIN(20, bufB)                  // newest 20 = run(A) stores -> B ready
        ASM_LOAD10(bufA, t0 + 2 * SCH)     // chunks 2,4,...,24 (<=960: in bounds)
        RUN_CHUNK40(bufB, t0 + SCH)        // 20 stores
        WAITPIN(20, bufA)                  // newest 20 = run(B) stores -> A ready
    }
    RUN_CHUNK40(bufA, (NCH - 1) * SCH)     // chunk 24: ticks 960..999
}

extern "C" void kernel_launch(void* const* d_in, const int* in_sizes, int n_in,
                              void* d_out, int out_size, void* d_ws, size_t ws_size,
                              hipStream_t stream) {
    const int*   ticks   = (const int*)d_in[0];
    const int*   xs      = (const int*)d_in[1];
    const int*   ys      = (const int*)d_in[2];
    const float* vals    = (const float*)d_in[3];
    const float* W       = (const float*)d_in[4];
    const int*   stridep = (const int*)d_in[5];
    float* ws  = (float*)d_ws;
    float* out = (float*)d_out;
    int n = in_sizes[0];
    unsigned long long wsz = (unsigned long long)ws_size;

    int nbh = 0;
    if (ws_size >= (size_t)HOT_OFF_B + 8 * (size_t)HOT_SLAB_B) {
        size_t fit = (ws_size - HOT_OFF_B) / HOT_SLAB_B;
        nbh = fit < NBH_MAX ? (int)fit : NBH_MAX;
    }

    zero_kernel<<<1024, 256, 0, stream>>>(ws, stridep, wsz);
    if (nbh > 0) {
        scatter_hot<<<nbh, SH_THREADS, 0, stream>>>(ticks, xs, ys, vals,
                                                    stridep, ws, wsz, n);
        int ngroups = (nbh + RED_GROUP - 1) / RED_GROUP;
        int rthreads = HOT_BINS * ngroups;
        reduce_hot<<<(rthreads + 255) / 256, 256, 0, stream>>>(stridep, ws, wsz,
                                                               nbh, ngroups);
    } else {
        scatter_kernel<<<(n + 255) / 256, 256, 0, stream>>>(ticks, xs, ys, vals,
                                                            stridep, ws, wsz, n);
    }
    combine_kernel<<<(BUF_ELEMS + 255) / 256, 256, 0, stream>>>(stridep, ws, wsz);
    matmul_kernel<<<(P_ELEMS + 255) / 256, 256, 0, stream>>>(W, ws);
    sim_kernel<<<2, 64, 0, stream>>>(ws, out);
}